// Round 1
// baseline (420.603 us; speedup 1.0000x reference)
//
#include <hip/hip_runtime.h>

#define BB 64
#define PP 8732
#define OO 32
#define CC 81
#define NEGPOS 3

// ---------------- workspace layout ----------------
// 0      : float acc[4]  {conf_pos_sum, loc_abs_sum, conf_hard_sum, pad}
// 16     : int n_pos_total
// 64     : u64 best[B*O]                (16384 B)  <- memset region ends 16448
// 16448  : float ov_fp[B*P]             (2235392 B)
// +      : int   obj_fp[B*P]
// +      : int   lab[B*P]
// +      : float ce_neg[B*P]
// +      : int   npos_b[B]
#define WS_OVFP   16448
#define WS_OBJFP  (WS_OVFP + BB*PP*4)
#define WS_LAB    (WS_OBJFP + BB*PP*4)
#define WS_CENEG  (WS_LAB + BB*PP*4)
#define WS_NPOSB  (WS_CENEG + BB*PP*4)

// ---------------- kernel 1a: IoU + per-prior argmax + per-object argmax ----------------
// grid (4, B), block 256. slice of 2183 priors per block (4*2183 == 8732).
__global__ __launch_bounds__(256) void match_a(
    const float* __restrict__ boxes, const float* __restrict__ priors,
    float* __restrict__ ovfp, int* __restrict__ objfp,
    unsigned long long* __restrict__ best)
{
    const int b = blockIdx.y, sl = blockIdx.x, tid = threadIdx.x;
    const float* bx = boxes + b * OO * 4;

    unsigned long long obest[OO];
#pragma unroll
    for (int o = 0; o < OO; ++o) obest[o] = 0ull;

    const int pstart = sl * 2183;
    const int pend = pstart + 2183;
    for (int p = pstart + tid; p < pend; p += 256) {
        float4 pr = ((const float4*)priors)[p];
        float plx = pr.x - pr.z * 0.5f, ply = pr.y - pr.w * 0.5f;
        float phx = pr.x + pr.z * 0.5f, phy = pr.y + pr.w * 0.5f;
        float parea = pr.z * pr.w;
        float bestv = -1.0f; int besto = 0;
#pragma unroll
        for (int o = 0; o < OO; ++o) {
            float b0 = bx[o*4+0], b1 = bx[o*4+1], b2 = bx[o*4+2], b3 = bx[o*4+3];
            float lox = fmaxf(b0, plx), loy = fmaxf(b1, ply);
            float hix = fminf(b2, phx), hiy = fminf(b3, phy);
            float inter = fmaxf(hix - lox, 0.0f) * fmaxf(hiy - loy, 0.0f);
            float iou = inter / ((b2 - b0) * (b3 - b1) + parea - inter);
            if (iou > bestv) { bestv = iou; besto = o; }  // strict > : first-max (np.argmax axis=0)
            unsigned long long enc =
                ((unsigned long long)__float_as_uint(iou) << 32) | (unsigned)(~(unsigned)p);
            obest[o] = (enc > obest[o]) ? enc : obest[o];  // max iou, tie -> min p
        }
        ovfp[b * PP + p] = bestv;
        objfp[b * PP + p] = besto;
    }

    // wave-reduce the 32 per-object bests, one global atomic per wave per object
#pragma unroll
    for (int o = 0; o < OO; ++o) {
        unsigned long long v = obest[o];
        for (int off = 32; off > 0; off >>= 1) {
            unsigned long long w = __shfl_down(v, off, 64);
            v = (w > v) ? w : v;
        }
        if ((tid & 63) == 0) atomicMax(&best[b * OO + o], v);
    }
}

// ---------------- kernel 1b: overrides + labels + loc loss ----------------
// grid B, block 256
__global__ __launch_bounds__(256) void match_b(
    const float* __restrict__ pred_locs, const float* __restrict__ boxes,
    const int* __restrict__ labels, const float* __restrict__ priors,
    const float* __restrict__ ovfp, const int* __restrict__ objfp,
    const unsigned long long* __restrict__ best,
    int* __restrict__ lab_out, int* __restrict__ npos_b,
    float* __restrict__ acc, int* __restrict__ nptot)
{
    const int b = blockIdx.x, tid = threadIdx.x;
    int pfo[OO];
#pragma unroll
    for (int o = 0; o < OO; ++o)
        pfo[o] = (int)(~(unsigned)(best[b * OO + o] & 0xFFFFFFFFull));

    float lsum = 0.0f; int lpos = 0;
    for (int p = tid; p < PP; p += 256) {
        int o = objfp[b * PP + p];
        float ov = ovfp[b * PP + p];
        // forced positives; ascending oo => last-write-wins (numpy scatter semantics)
#pragma unroll
        for (int oo = 0; oo < OO; ++oo)
            if (pfo[oo] == p) { o = oo; ov = 1.0f; }
        int lab = (ov < 0.5f) ? 0 : labels[b * OO + o];
        lab_out[b * PP + p] = lab;
        if (lab != 0) {
            lpos++;
            float4 bo = ((const float4*)boxes)[b * OO + o];
            float4 pr = ((const float4*)priors)[p];
            float gx = ((bo.x + bo.z) * 0.5f - pr.x) / (pr.z * 0.1f);
            float gy = ((bo.y + bo.w) * 0.5f - pr.y) / (pr.w * 0.1f);
            float gw = logf((bo.z - bo.x) / pr.z) * 5.0f;
            float gh = logf((bo.w - bo.y) / pr.w) * 5.0f;
            float4 pl = ((const float4*)pred_locs)[b * PP + p];
            lsum += fabsf(pl.x - gx) + fabsf(pl.y - gy) + fabsf(pl.z - gw) + fabsf(pl.w - gh);
        }
    }
    __shared__ float sred[4];
    __shared__ int sredi[4];
    for (int off = 32; off > 0; off >>= 1) {
        lsum += __shfl_down(lsum, off, 64);
        lpos += __shfl_down(lpos, off, 64);
    }
    if ((tid & 63) == 0) { sred[tid >> 6] = lsum; sredi[tid >> 6] = lpos; }
    __syncthreads();
    if (tid == 0) {
        float s = 0.0f; int n = 0;
        for (int w = 0; w < 4; ++w) { s += sred[w]; n += sredi[w]; }
        atomicAdd(&acc[1], s);
        npos_b[b] = n;
        atomicAdd(nptot, n);
    }
}

// ---------------- kernel 2: cross entropy ----------------
// grid B*P/128 = 4366, block 128. LDS-staged coalesced reads.
__global__ __launch_bounds__(128) void ce_kernel(
    const float* __restrict__ scores, const int* __restrict__ lab,
    float* __restrict__ ce_neg, float* __restrict__ acc)
{
    __shared__ float ss[128 * CC];   // 41472 B
    const int tid = threadIdx.x;
    const long long base = (long long)blockIdx.x * 128 * CC;
    for (int i = tid; i < 128 * CC; i += 128) ss[i] = scores[base + i];
    __syncthreads();

    const int bp = blockIdx.x * 128 + tid;
    const float* v = ss + tid * CC;   // stride 81: odd -> at worst 2-way bank aliasing (free)
    float m = v[0];
#pragma unroll
    for (int c = 1; c < CC; ++c) m = fmaxf(m, v[c]);
    float sum = 0.0f;
#pragma unroll
    for (int c = 0; c < CC; ++c) sum += __expf(v[c] - m);
    float lse = m + __logf(sum);
    int l = lab[bp];
    float ce = lse - v[l];
    float pos = (l != 0) ? ce : 0.0f;
    ce_neg[bp] = (l != 0) ? 0.0f : ce;

    for (int off = 32; off > 0; off >>= 1) pos += __shfl_down(pos, off, 64);
    __shared__ float sr[2];
    if ((tid & 63) == 0) sr[tid >> 6] = pos;
    __syncthreads();
    if (tid == 0) atomicAdd(&acc[0], sr[0] + sr[1]);
}

// ---------------- kernel 3: per-batch exact top-K sum via radix select ----------------
// grid B, block 256
__global__ __launch_bounds__(256) void topk_kernel(
    const float* __restrict__ ce_neg, const int* __restrict__ npos_b,
    float* __restrict__ acc)
{
    __shared__ float sv[PP];      // 34928 B
    __shared__ int hist[256];
    __shared__ unsigned sel[2];
    const int b = blockIdx.x, tid = threadIdx.x;
    for (int p = tid; p < PP; p += 256) sv[p] = ce_neg[b * PP + p];
    int K = NEGPOS * npos_b[b];
    if (K > PP) K = PP;
    __syncthreads();
    if (K <= 0) return;   // contributes 0 (can't happen: forced positives)

    unsigned prefix = 0, mask = 0;
    unsigned remaining = (unsigned)K;
    for (int pass = 0; pass < 4; ++pass) {
        const int shift = 24 - 8 * pass;
        hist[tid] = 0;
        __syncthreads();
        for (int p = tid; p < PP; p += 256) {
            unsigned u = __float_as_uint(sv[p]);   // all ce >= 0: bits monotone
            if ((u & mask) == prefix) atomicAdd(&hist[(u >> shift) & 255], 1);
        }
        __syncthreads();
        if (tid == 0) {
            unsigned cum = 0; int binsel = 0;
            for (int i = 255; i >= 0; --i) {
                unsigned h = (unsigned)hist[i];
                if (cum + h >= remaining) { binsel = i; break; }
                cum += h;
            }
            sel[0] = (unsigned)binsel;
            sel[1] = remaining - cum;
        }
        __syncthreads();
        prefix |= sel[0] << shift;
        mask |= 0xFFu << shift;
        remaining = sel[1];
        __syncthreads();
    }
    // prefix = bit pattern of K-th largest; remaining = # cutoff-valued elems inside top-K
    float sgt = 0.0f;
    for (int p = tid; p < PP; p += 256) {
        unsigned u = __float_as_uint(sv[p]);
        if (u > prefix) sgt += sv[p];
    }
    for (int off = 32; off > 0; off >>= 1) sgt += __shfl_down(sgt, off, 64);
    __shared__ float sr[4];
    if ((tid & 63) == 0) sr[tid >> 6] = sgt;
    __syncthreads();
    if (tid == 0) {
        float hard = sr[0] + sr[1] + sr[2] + sr[3]
                   + __uint_as_float(prefix) * (float)remaining;
        atomicAdd(&acc[2], hard);
    }
}

// ---------------- kernel 4: finalize ----------------
__global__ void finalize_kernel(const float* __restrict__ acc,
                                const int* __restrict__ nptot,
                                float* __restrict__ out)
{
    float n = (float)(*nptot);
    out[0] = (acc[2] + acc[0]) / n + acc[1] / (n * 4.0f);
}

extern "C" void kernel_launch(void* const* d_in, const int* in_sizes, int n_in,
                              void* d_out, int out_size, void* d_ws, size_t ws_size,
                              hipStream_t stream) {
    const float* pred_locs   = (const float*)d_in[0];   // [B,P,4]
    const float* pred_scores = (const float*)d_in[1];   // [B,P,C]
    const float* boxes       = (const float*)d_in[2];   // [B,O,4]
    const int*   labels      = (const int*)d_in[3];     // [B,O]
    const float* priors      = (const float*)d_in[4];   // [P,4] cxcywh
    float* out = (float*)d_out;

    char* ws = (char*)d_ws;
    float* acc = (float*)ws;                      // [0]=conf_pos [1]=loc_abs [2]=conf_hard
    int* nptot = (int*)(ws + 16);
    unsigned long long* best = (unsigned long long*)(ws + 64);
    float* ovfp   = (float*)(ws + WS_OVFP);
    int*   objfp  = (int*)(ws + WS_OBJFP);
    int*   lab    = (int*)(ws + WS_LAB);
    float* ce_neg = (float*)(ws + WS_CENEG);
    int*   nposb  = (int*)(ws + WS_NPOSB);

    // zero accumulators + best[] (poisoned 0xAA before every timed launch)
    hipMemsetAsync(d_ws, 0, 64 + BB * OO * 8, stream);

    match_a<<<dim3(4, BB), 256, 0, stream>>>(boxes, priors, ovfp, objfp, best);
    match_b<<<BB, 256, 0, stream>>>(pred_locs, boxes, labels, priors,
                                    ovfp, objfp, best, lab, nposb, acc, nptot);
    ce_kernel<<<(BB * PP) / 128, 128, 0, stream>>>(pred_scores, lab, ce_neg, acc);
    topk_kernel<<<BB, 256, 0, stream>>>(ce_neg, nposb, acc);
    finalize_kernel<<<1, 1, 0, stream>>>(acc, nptot, out);
}